// Round 1
// baseline (932.688 us; speedup 1.0000x reference)
//
#include <hip/hip_runtime.h>
#include <hip/hip_bf16.h>

#define N_VOCAB 50257
#define N_PAD   50304   // 393 * 128
#define D_K     1024
#define M_ROWS  2048

typedef __attribute__((ext_vector_type(8))) short bf16x8;
typedef __attribute__((ext_vector_type(4))) float f32x4;

__device__ inline void async_copy16(const __hip_bfloat16* g, __hip_bfloat16* l) {
  auto* gp = (const __attribute__((address_space(1))) unsigned int*)g;
  auto* lp = (__attribute__((address_space(3))) unsigned int*)l;
  __builtin_amdgcn_global_load_lds(gp, lp, 16, 0, 0);
}

// bf16 bits of a small-int float (exact for |v| <= 256)
__device__ inline short qbits(float v, float s) {
  float q = fminf(fmaxf(rintf(v / s), -8.f), 7.f);
  return (short)(__float_as_uint(q) >> 16);
}

// ---------------- absmax reduction ----------------
__global__ void absmax_kernel(const float4* __restrict__ p, int n4,
                              unsigned* __restrict__ out) {
  float m = 0.f;
  for (int i = blockIdx.x * blockDim.x + threadIdx.x; i < n4;
       i += gridDim.x * blockDim.x) {
    float4 v = p[i];
    m = fmaxf(m, fmaxf(fmaxf(fabsf(v.x), fabsf(v.y)),
                       fmaxf(fabsf(v.z), fabsf(v.w))));
  }
#pragma unroll
  for (int off = 32; off; off >>= 1) m = fmaxf(m, __shfl_xor(m, off));
  __shared__ float red[4];
  int tid = threadIdx.x;
  if ((tid & 63) == 0) red[tid >> 6] = m;
  __syncthreads();
  if (tid == 0) {
    m = fmaxf(fmaxf(red[0], red[1]), fmaxf(red[2], red[3]));
    atomicMax(out, __float_as_uint(m));
  }
}

// ---------------- quantize x -> bf16 ints ----------------
__global__ void quant_x_kernel(const float4* __restrict__ x,
                               short4* __restrict__ qx,
                               const unsigned* __restrict__ amax, int n4) {
  int i = blockIdx.x * blockDim.x + threadIdx.x;
  if (i >= n4) return;
  float s = __uint_as_float(amax[0]) * (1.0f / 7.0f);
  float4 v = x[i];
  short4 q;
  q.x = qbits(v.x, s); q.y = qbits(v.y, s);
  q.z = qbits(v.z, s); q.w = qbits(v.w, s);
  qx[i] = q;
}

// ---------------- quantize W -> bf16 ints (zero-padded rows) ----------------
__global__ void quant_w_kernel(const float4* __restrict__ Wp,
                               short4* __restrict__ qw,
                               const unsigned* __restrict__ amax,
                               int n4_valid, int n4_total) {
  int i = blockIdx.x * blockDim.x + threadIdx.x;
  if (i >= n4_total) return;
  short4 q = {0, 0, 0, 0};
  if (i < n4_valid) {
    float s = __uint_as_float(amax[1]) * (1.0f / 7.0f);
    float4 v = Wp[i];
    q.x = qbits(v.x, s); q.y = qbits(v.y, s);
    q.z = qbits(v.z, s); q.w = qbits(v.w, s);
  }
  qw[i] = q;
}

// ---------------- bias fake-quant ----------------
__global__ void bq_kernel(const float* __restrict__ b, float* __restrict__ bq,
                          const unsigned* __restrict__ amax) {
  int i = blockIdx.x * blockDim.x + threadIdx.x;
  if (i >= N_PAD) return;
  float v = 0.f;
  if (i < N_VOCAB) {
    float sb = (__uint_as_float(amax[0]) * (1.0f / 7.0f)) *
               (__uint_as_float(amax[1]) * (1.0f / 7.0f));
    v = rintf(b[i] / sb) * sb;
  }
  bq[i] = v;
}

// ---------------- GEMM: logits = (sx*sw) * qx·qw^T + bq ----------------
// 128x128 tile, 4 waves (2x2 of 64x64), BK=32, double-buffered LDS,
// global_load_lds width-16 staging. mfma_f32_16x16x32_bf16.
__global__ __launch_bounds__(256, 3) void gemm_kernel(
    const __hip_bfloat16* __restrict__ qx,   // [2048][1024]
    const __hip_bfloat16* __restrict__ qw,   // [50304][1024]
    const float* __restrict__ bq,            // [50304]
    const unsigned* __restrict__ amax,
    float* __restrict__ outp)                // [2048][50257]
{
  constexpr int BK = 32;
  __shared__ __hip_bfloat16 sA[2][128 * BK];
  __shared__ __hip_bfloat16 sB[2][128 * BK];

  const int tid = threadIdx.x;
  const int l = tid & 63;
  const int w = tid >> 6;
  const int wr = w >> 1, wc = w & 1;
  const int m0 = blockIdx.y * 128;
  const int n0 = blockIdx.x * 128;

  const float sx = __uint_as_float(amax[0]) * (1.0f / 7.0f);
  const float sw = __uint_as_float(amax[1]) * (1.0f / 7.0f);
  const float scale = sx * sw;

  f32x4 acc[4][4] = {};

  // staging: per wave 2 chunks of 1KB each for A and B.
  // chunk c = 16 rows of 32 bf16; lane l -> row c*16 + (l>>2), col (l&3)*8
  const int srow = (l >> 2);
  const int scol = (l & 3) * 8;

  auto stage = [&](int buf, int k0) {
#pragma unroll
    for (int i = 0; i < 2; ++i) {
      int c = w * 2 + i;
      int row = c * 16 + srow;
      async_copy16(qx + (size_t)(m0 + row) * D_K + k0 + scol,
                   &sA[buf][c * 512]);
      async_copy16(qw + (size_t)(n0 + row) * D_K + k0 + scol,
                   &sB[buf][c * 512]);
    }
  };

  stage(0, 0);
  __syncthreads();

  int cur = 0;
  constexpr int NT = D_K / BK;  // 32
  for (int kt = 0; kt < NT; ++kt) {
    if (kt + 1 < NT) stage(cur ^ 1, (kt + 1) * BK);

    bf16x8 af[4], bfr[4];
#pragma unroll
    for (int mi = 0; mi < 4; ++mi) {
      int row = wr * 64 + mi * 16 + (l & 15);
      af[mi] = *(const bf16x8*)&sA[cur][row * BK + (l >> 4) * 8];
    }
#pragma unroll
    for (int ni = 0; ni < 4; ++ni) {
      int row = wc * 64 + ni * 16 + (l & 15);
      bfr[ni] = *(const bf16x8*)&sB[cur][row * BK + (l >> 4) * 8];
    }
#pragma unroll
    for (int mi = 0; mi < 4; ++mi)
#pragma unroll
      for (int ni = 0; ni < 4; ++ni)
        acc[mi][ni] = __builtin_amdgcn_mfma_f32_16x16x32_bf16(
            af[mi], bfr[ni], acc[mi][ni], 0, 0, 0);

    __syncthreads();
    cur ^= 1;
  }

  // epilogue: C[row][col], col = lane&15 (+16*ni), row = (lane>>4)*4 + r
#pragma unroll
  for (int ni = 0; ni < 4; ++ni) {
    int col = n0 + wc * 64 + ni * 16 + (l & 15);
    if (col < N_VOCAB) {
      float bb = bq[col];
#pragma unroll
      for (int mi = 0; mi < 4; ++mi) {
#pragma unroll
        for (int r = 0; r < 4; ++r) {
          int row = m0 + wr * 64 + mi * 16 + (l >> 4) * 4 + r;
          outp[(size_t)row * N_VOCAB + col] = acc[mi][ni][r] * scale + bb;
        }
      }
    }
  }
}

// ---------------- per-row log-softmax (in place) ----------------
__global__ __launch_bounds__(256) void softmax_kernel(float* __restrict__ out) {
  const int m = blockIdx.x;
  float* row = out + (size_t)m * N_VOCAB;
  const int tid = threadIdx.x;
  __shared__ float red[8];

  float mx = -3.4e38f;
  for (int i = tid; i < N_VOCAB; i += 256) mx = fmaxf(mx, row[i]);
#pragma unroll
  for (int off = 32; off; off >>= 1) mx = fmaxf(mx, __shfl_xor(mx, off));
  if ((tid & 63) == 0) red[tid >> 6] = mx;
  __syncthreads();
  mx = fmaxf(fmaxf(red[0], red[1]), fmaxf(red[2], red[3]));

  float s = 0.f;
  for (int i = tid; i < N_VOCAB; i += 256) s += __expf(row[i] - mx);
#pragma unroll
  for (int off = 32; off; off >>= 1) s += __shfl_xor(s, off);
  if ((tid & 63) == 0) red[4 + (tid >> 6)] = s;
  __syncthreads();
  s = red[4] + red[5] + red[6] + red[7];

  float lz = mx + __logf(s);
  for (int i = tid; i < N_VOCAB; i += 256) row[i] -= lz;
}

extern "C" void kernel_launch(void* const* d_in, const int* in_sizes, int n_in,
                              void* d_out, int out_size, void* d_ws,
                              size_t ws_size, hipStream_t stream) {
  const float* x = (const float*)d_in[0];
  const float* W = (const float*)d_in[1];
  const float* b = (const float*)d_in[2];
  float* out = (float*)d_out;

  char* ws = (char*)d_ws;
  unsigned* amax = (unsigned*)ws;                           // 8 B
  float* bq = (float*)(ws + 4096);                          // 201,216 B
  __hip_bfloat16* qx = (__hip_bfloat16*)(ws + (1 << 20));   // 4 MB
  __hip_bfloat16* qw = (__hip_bfloat16*)(ws + (8ull << 20)); // 103 MB

  hipMemsetAsync(amax, 0, 8, stream);

  const int nx4 = (M_ROWS * D_K) / 4;                       // 524288
  const int nw4 = (N_VOCAB * D_K) / 4;                      // 12865792
  const int nt4 = (N_PAD * D_K) / 4;                        // 12877824

  absmax_kernel<<<512, 256, 0, stream>>>((const float4*)x, nx4, amax + 0);
  absmax_kernel<<<2048, 256, 0, stream>>>((const float4*)W, nw4, amax + 1);

  quant_x_kernel<<<nx4 / 256, 256, 0, stream>>>((const float4*)x, (short4*)qx,
                                                amax, nx4);
  quant_w_kernel<<<nt4 / 256, 256, 0, stream>>>((const float4*)W, (short4*)qw,
                                                amax, nw4, nt4);
  bq_kernel<<<(N_PAD + 255) / 256, 256, 0, stream>>>(b, bq, amax);

  dim3 grid(N_PAD / 128, M_ROWS / 128);  // (393, 16)
  gemm_kernel<<<grid, 256, 0, stream>>>(qx, qw, bq, amax, out);

  softmax_kernel<<<M_ROWS, 256, 0, stream>>>(out);
}

// Round 2
// 677.820 us; speedup vs baseline: 1.3760x; 1.3760x over previous
//
#include <hip/hip_runtime.h>
#include <hip/hip_bf16.h>

#define N_VOCAB 50257
#define N_PAD   50304   // 393 * 128
#define NB      393     // n-blocks
#define D_K     1024
#define M_ROWS  2048

typedef __attribute__((ext_vector_type(8))) short bf16x8;
typedef __attribute__((ext_vector_type(4))) float f32x4;

__device__ inline void async_copy16(const __hip_bfloat16* g, __hip_bfloat16* l) {
  auto* gp = (const __attribute__((address_space(1))) unsigned int*)g;
  auto* lp = (__attribute__((address_space(3))) unsigned int*)l;
  __builtin_amdgcn_global_load_lds(gp, lp, 16, 0, 0);
}

// bf16 bits of a small-int float (exact for |v| <= 256)
__device__ inline short qbits(float v, float s) {
  float q = fminf(fmaxf(rintf(v / s), -8.f), 7.f);
  return (short)(__float_as_uint(q) >> 16);
}

// ---------------- absmax reduction ----------------
__global__ void absmax_kernel(const float4* __restrict__ p, int n4,
                              unsigned* __restrict__ out) {
  float m = 0.f;
  for (int i = blockIdx.x * blockDim.x + threadIdx.x; i < n4;
       i += gridDim.x * blockDim.x) {
    float4 v = p[i];
    m = fmaxf(m, fmaxf(fmaxf(fabsf(v.x), fabsf(v.y)),
                       fmaxf(fabsf(v.z), fabsf(v.w))));
  }
#pragma unroll
  for (int off = 32; off; off >>= 1) m = fmaxf(m, __shfl_xor(m, off));
  __shared__ float red[4];
  int tid = threadIdx.x;
  if ((tid & 63) == 0) red[tid >> 6] = m;
  __syncthreads();
  if (tid == 0) {
    m = fmaxf(fmaxf(red[0], red[1]), fmaxf(red[2], red[3]));
    atomicMax(out, __float_as_uint(m));
  }
}

// ---------------- quantize x -> bf16 ints ----------------
__global__ void quant_x_kernel(const float4* __restrict__ x,
                               short4* __restrict__ qx,
                               const unsigned* __restrict__ amax, int n4) {
  int i = blockIdx.x * blockDim.x + threadIdx.x;
  if (i >= n4) return;
  float s = __uint_as_float(amax[0]) * (1.0f / 7.0f);
  float4 v = x[i];
  short4 q;
  q.x = qbits(v.x, s); q.y = qbits(v.y, s);
  q.z = qbits(v.z, s); q.w = qbits(v.w, s);
  qx[i] = q;
}

// ---------------- quantize W -> bf16 ints (zero-padded rows) ----------------
__global__ void quant_w_kernel(const float4* __restrict__ Wp,
                               short4* __restrict__ qw,
                               const unsigned* __restrict__ amax,
                               int n4_valid, int n4_total) {
  int i = blockIdx.x * blockDim.x + threadIdx.x;
  if (i >= n4_total) return;
  short4 q = {0, 0, 0, 0};
  if (i < n4_valid) {
    float s = __uint_as_float(amax[1]) * (1.0f / 7.0f);
    float4 v = Wp[i];
    q.x = qbits(v.x, s); q.y = qbits(v.y, s);
    q.z = qbits(v.z, s); q.w = qbits(v.w, s);
  }
  qw[i] = q;
}

// ---------------- bias fake-quant ----------------
__global__ void bq_kernel(const float* __restrict__ b, float* __restrict__ bq,
                          const unsigned* __restrict__ amax) {
  int i = blockIdx.x * blockDim.x + threadIdx.x;
  if (i >= N_PAD) return;
  float v = 0.f;
  if (i < N_VOCAB) {
    float sb = (__uint_as_float(amax[0]) * (1.0f / 7.0f)) *
               (__uint_as_float(amax[1]) * (1.0f / 7.0f));
    v = rintf(b[i] / sb) * sb;
  }
  bq[i] = v;
}

// ---------------- GEMM + fused per-block softmax partials ----------------
// 128x128 tile, 4 waves (2x2 of 64x64), BK=32, double-buffered LDS,
// global_load_lds width-16 staging. mfma_f32_16x16x32_bf16.
// grid: x = m-tile (16, fastest) so B-panels are L2-reused across m.
__global__ __launch_bounds__(256, 3) void gemm_kernel(
    const __hip_bfloat16* __restrict__ qx,   // [2048][1024]
    const __hip_bfloat16* __restrict__ qw,   // [50304][1024]
    const float* __restrict__ bq,            // [50304]
    const unsigned* __restrict__ amax,
    float* __restrict__ outp,                // [2048][50257]
    float* __restrict__ pmax,                // [2048][NB]
    float* __restrict__ psum)                // [2048][NB]
{
  constexpr int BK = 32;
  __shared__ __hip_bfloat16 sA[2][128 * BK];
  __shared__ __hip_bfloat16 sB[2][128 * BK];
  __shared__ float redMax[128][2];
  __shared__ float redSum[128][2];

  const int tid = threadIdx.x;
  const int l = tid & 63;
  const int w = tid >> 6;
  const int wr = w >> 1, wc = w & 1;
  const int m0 = blockIdx.x * 128;
  const int n0 = blockIdx.y * 128;
  const int nb = blockIdx.y;

  const float sx = __uint_as_float(amax[0]) * (1.0f / 7.0f);
  const float sw = __uint_as_float(amax[1]) * (1.0f / 7.0f);
  const float scale = sx * sw;

  f32x4 acc[4][4] = {};

  const int srow = (l >> 2);
  const int scol = (l & 3) * 8;

  auto stage = [&](int buf, int k0) {
#pragma unroll
    for (int i = 0; i < 2; ++i) {
      int c = w * 2 + i;
      int row = c * 16 + srow;
      async_copy16(qx + (size_t)(m0 + row) * D_K + k0 + scol,
                   &sA[buf][c * 512]);
      async_copy16(qw + (size_t)(n0 + row) * D_K + k0 + scol,
                   &sB[buf][c * 512]);
    }
  };

  stage(0, 0);
  __syncthreads();

  int cur = 0;
  constexpr int NT = D_K / BK;  // 32
  for (int kt = 0; kt < NT; ++kt) {
    if (kt + 1 < NT) stage(cur ^ 1, (kt + 1) * BK);

    bf16x8 af[4], bfr[4];
#pragma unroll
    for (int mi = 0; mi < 4; ++mi) {
      int row = wr * 64 + mi * 16 + (l & 15);
      af[mi] = *(const bf16x8*)&sA[cur][row * BK + (l >> 4) * 8];
    }
#pragma unroll
    for (int ni = 0; ni < 4; ++ni) {
      int row = wc * 64 + ni * 16 + (l & 15);
      bfr[ni] = *(const bf16x8*)&sB[cur][row * BK + (l >> 4) * 8];
    }
#pragma unroll
    for (int mi = 0; mi < 4; ++mi)
#pragma unroll
      for (int ni = 0; ni < 4; ++ni)
        acc[mi][ni] = __builtin_amdgcn_mfma_f32_16x16x32_bf16(
            af[mi], bfr[ni], acc[mi][ni], 0, 0, 0);

    __syncthreads();
    cur ^= 1;
  }

  // ---- epilogue: scale + bias, store logits, fused softmax partials ----
  // C layout: col = n0 + wc*64 + ni*16 + (l&15); row = m0 + wr*64 + mi*16 + (l>>4)*4 + r
  bool valid[4];
  float bb[4];
#pragma unroll
  for (int ni = 0; ni < 4; ++ni) {
    int col = n0 + wc * 64 + ni * 16 + (l & 15);
    valid[ni] = (col < N_VOCAB);
    bb[ni] = valid[ni] ? bq[col] : 0.f;
  }

#pragma unroll
  for (int mi = 0; mi < 4; ++mi)
#pragma unroll
    for (int ni = 0; ni < 4; ++ni)
#pragma unroll
      for (int r = 0; r < 4; ++r)
        acc[mi][ni][r] = acc[mi][ni][r] * scale + bb[ni];

  // store logits
#pragma unroll
  for (int ni = 0; ni < 4; ++ni) {
    if (valid[ni]) {
      int col = n0 + wc * 64 + ni * 16 + (l & 15);
#pragma unroll
      for (int mi = 0; mi < 4; ++mi)
#pragma unroll
        for (int r = 0; r < 4; ++r) {
          int row = m0 + wr * 64 + mi * 16 + (l >> 4) * 4 + r;
          outp[(size_t)row * N_VOCAB + col] = acc[mi][ni][r];
        }
    }
  }

  // per-row max over this wave's 64 cols (reduce ni, then 16 lanes)
  float rmax[4][4];
#pragma unroll
  for (int mi = 0; mi < 4; ++mi)
#pragma unroll
    for (int r = 0; r < 4; ++r) {
      float mval = -3.4e38f;
#pragma unroll
      for (int ni = 0; ni < 4; ++ni)
        if (valid[ni]) mval = fmaxf(mval, acc[mi][ni][r]);
#pragma unroll
      for (int off = 1; off < 16; off <<= 1)
        mval = fmaxf(mval, __shfl_xor(mval, off));
      rmax[mi][r] = mval;
      if ((l & 15) == 0)
        redMax[wr * 64 + mi * 16 + (l >> 4) * 4 + r][wc] = mval;
    }
  __syncthreads();

  // combine across wc pair, sum-exp
#pragma unroll
  for (int mi = 0; mi < 4; ++mi)
#pragma unroll
    for (int r = 0; r < 4; ++r) {
      int rl = wr * 64 + mi * 16 + (l >> 4) * 4 + r;
      float gmax = fmaxf(redMax[rl][0], redMax[rl][1]);
      float s = 0.f;
#pragma unroll
      for (int ni = 0; ni < 4; ++ni)
        if (valid[ni]) s += __expf(acc[mi][ni][r] - gmax);
#pragma unroll
      for (int off = 1; off < 16; off <<= 1)
        s += __shfl_xor(s, off);
      if ((l & 15) == 0) redSum[rl][wc] = s;
      rmax[mi][r] = gmax;  // keep combined max
    }
  __syncthreads();

  if (wc == 0 && (l & 15) == 0) {
#pragma unroll
    for (int mi = 0; mi < 4; ++mi)
#pragma unroll
      for (int r = 0; r < 4; ++r) {
        int rl = wr * 64 + mi * 16 + (l >> 4) * 4 + r;
        int rowg = m0 + rl;
        pmax[(size_t)rowg * NB + nb] = rmax[mi][r];
        psum[(size_t)rowg * NB + nb] = redSum[rl][0] + redSum[rl][1];
      }
  }
}

// ---------------- finalize: per-row logZ from partials ----------------
__global__ __launch_bounds__(256) void finalize_kernel(
    const float* __restrict__ pmax, const float* __restrict__ psum,
    float* __restrict__ logz) {
  const int row = blockIdx.x;
  const float* pm = pmax + (size_t)row * NB;
  const float* ps = psum + (size_t)row * NB;
  const int tid = threadIdx.x;
  __shared__ float red[8];

  float m = -3.4e38f;
  for (int i = tid; i < NB; i += 256) m = fmaxf(m, pm[i]);
#pragma unroll
  for (int off = 32; off; off >>= 1) m = fmaxf(m, __shfl_xor(m, off));
  if ((tid & 63) == 0) red[tid >> 6] = m;
  __syncthreads();
  m = fmaxf(fmaxf(red[0], red[1]), fmaxf(red[2], red[3]));

  float s = 0.f;
  for (int i = tid; i < NB; i += 256) s += ps[i] * __expf(pm[i] - m);
#pragma unroll
  for (int off = 32; off; off >>= 1) s += __shfl_xor(s, off);
  if ((tid & 63) == 0) red[4 + (tid >> 6)] = s;
  __syncthreads();
  if (tid == 0) {
    s = red[4] + red[5] + red[6] + red[7];
    logz[row] = m + __logf(s);
  }
}

// ---------------- subtract logZ (in place over flat out) ----------------
__global__ __launch_bounds__(256) void subtract_kernel(
    float4* __restrict__ out, const float* __restrict__ logz, int n4) {
  for (int i = blockIdx.x * blockDim.x + threadIdx.x; i < n4;
       i += gridDim.x * blockDim.x) {
    float4 v = out[i];
    unsigned base = (unsigned)i * 4u;
    v.x -= logz[(base + 0) / N_VOCAB];
    v.y -= logz[(base + 1) / N_VOCAB];
    v.z -= logz[(base + 2) / N_VOCAB];
    v.w -= logz[(base + 3) / N_VOCAB];
    out[i] = v;
  }
}

extern "C" void kernel_launch(void* const* d_in, const int* in_sizes, int n_in,
                              void* d_out, int out_size, void* d_ws,
                              size_t ws_size, hipStream_t stream) {
  const float* x = (const float*)d_in[0];
  const float* W = (const float*)d_in[1];
  const float* b = (const float*)d_in[2];
  float* out = (float*)d_out;

  char* ws = (char*)d_ws;
  unsigned* amax = (unsigned*)ws;                             // 8 B
  float* bq = (float*)(ws + 4096);                            // 201 KB
  float* logz = (float*)(ws + (1ull << 20));                  // 8 KB
  float* pmax = (float*)(ws + (2ull << 20));                  // 3.2 MB
  float* psum = (float*)(ws + (6ull << 20));                  // 3.2 MB
  __hip_bfloat16* qx = (__hip_bfloat16*)(ws + (10ull << 20)); // 4 MB
  __hip_bfloat16* qw = (__hip_bfloat16*)(ws + (16ull << 20)); // 103 MB

  hipMemsetAsync(amax, 0, 8, stream);

  const int nx4 = (M_ROWS * D_K) / 4;     // 524288
  const int nw4 = (N_VOCAB * D_K) / 4;    // 12865792
  const int nt4 = (N_PAD * D_K) / 4;      // 12877824

  absmax_kernel<<<512, 256, 0, stream>>>((const float4*)x, nx4, amax + 0);
  absmax_kernel<<<2048, 256, 0, stream>>>((const float4*)W, nw4, amax + 1);

  quant_x_kernel<<<nx4 / 256, 256, 0, stream>>>((const float4*)x, (short4*)qx,
                                                amax, nx4);
  quant_w_kernel<<<nt4 / 256, 256, 0, stream>>>((const float4*)W, (short4*)qw,
                                                amax, nw4, nt4);
  bq_kernel<<<(N_PAD + 255) / 256, 256, 0, stream>>>(b, bq, amax);

  dim3 grid(M_ROWS / 128, N_PAD / 128);  // (16, 393), m fastest
  gemm_kernel<<<grid, 256, 0, stream>>>(qx, qw, bq, amax, out, pmax, psum);

  finalize_kernel<<<M_ROWS, 256, 0, stream>>>(pmax, psum, logz);

  const int n4 = (M_ROWS * N_VOCAB) / 4;  // 25731584
  subtract_kernel<<<2048, 256, 0, stream>>>((float4*)out, logz, n4);
}

// Round 3
// 581.747 us; speedup vs baseline: 1.6033x; 1.1651x over previous
//
#include <hip/hip_runtime.h>
#include <hip/hip_bf16.h>

#define N_VOCAB 50257
#define NB      400     // n-block columns (padded)
#define N_PAD   51200   // 400 * 128
#define D_K     1024
#define M_ROWS  2048

typedef __attribute__((ext_vector_type(4))) int i32x4;

__device__ inline void async_copy16(const void* g, void* l) {
  auto* gp = (const __attribute__((address_space(1))) unsigned int*)g;
  auto* lp = (__attribute__((address_space(3))) unsigned int*)l;
  __builtin_amdgcn_global_load_lds(gp, lp, 16, 0, 0);
}

__device__ inline signed char qint(float v, float s) {
  float q = fminf(fmaxf(rintf(v / s), -8.f), 7.f);
  return (signed char)(int)q;
}

// ---------------- absmax reduction ----------------
__global__ void absmax_kernel(const float4* __restrict__ p, int n4,
                              unsigned* __restrict__ out) {
  float m = 0.f;
  for (int i = blockIdx.x * blockDim.x + threadIdx.x; i < n4;
       i += gridDim.x * blockDim.x) {
    float4 v = p[i];
    m = fmaxf(m, fmaxf(fmaxf(fabsf(v.x), fabsf(v.y)),
                       fmaxf(fabsf(v.z), fabsf(v.w))));
  }
#pragma unroll
  for (int off = 32; off; off >>= 1) m = fmaxf(m, __shfl_xor(m, off));
  __shared__ float red[4];
  int tid = threadIdx.x;
  if ((tid & 63) == 0) red[tid >> 6] = m;
  __syncthreads();
  if (tid == 0) {
    m = fmaxf(fmaxf(red[0], red[1]), fmaxf(red[2], red[3]));
    atomicMax(out, __float_as_uint(m));
  }
}

// ---------------- quantize x -> int8 ----------------
__global__ void quant_x_kernel(const float4* __restrict__ x,
                               char4* __restrict__ qx,
                               const unsigned* __restrict__ amax, int n4) {
  int i = blockIdx.x * blockDim.x + threadIdx.x;
  if (i >= n4) return;
  float s = __uint_as_float(amax[0]) * (1.0f / 7.0f);
  float4 v = x[i];
  char4 q;
  q.x = qint(v.x, s); q.y = qint(v.y, s);
  q.z = qint(v.z, s); q.w = qint(v.w, s);
  qx[i] = q;
}

// ---------------- quantize W -> int8 (zero-padded rows) ----------------
__global__ void quant_w_kernel(const float4* __restrict__ Wp,
                               char4* __restrict__ qw,
                               const unsigned* __restrict__ amax,
                               int n4_valid, int n4_total) {
  int i = blockIdx.x * blockDim.x + threadIdx.x;
  if (i >= n4_total) return;
  char4 q = {0, 0, 0, 0};
  if (i < n4_valid) {
    float s = __uint_as_float(amax[1]) * (1.0f / 7.0f);
    float4 v = Wp[i];
    q.x = qint(v.x, s); q.y = qint(v.y, s);
    q.z = qint(v.z, s); q.w = qint(v.w, s);
  }
  qw[i] = q;
}

// ---------------- bias fake-quant ----------------
__global__ void bq_kernel(const float* __restrict__ b, float* __restrict__ bq,
                          const unsigned* __restrict__ amax) {
  int i = blockIdx.x * blockDim.x + threadIdx.x;
  if (i >= N_PAD) return;
  float v = 0.f;
  if (i < N_VOCAB) {
    float sb = (__uint_as_float(amax[0]) * (1.0f / 7.0f)) *
               (__uint_as_float(amax[1]) * (1.0f / 7.0f));
    v = rintf(b[i] / sb) * sb;
  }
  bq[i] = v;
}

// ---------------- int8 GEMM + fused per-block softmax partials ----------------
// 128x128 tile, 4 waves (2x2 of 64x64), BK=64 (bytes), double-buffered LDS,
// global_load_lds width-16 staging with pre-swizzled source (T2-style
// kslot ^= row&3), mfma_i32_16x16x64_i8.
// 1D grid 6400 with bijective XCD swizzle: all 16 m-blocks of one n-column
// land on the same XCD -> B panel fetched once.
__global__ __launch_bounds__(256, 3) void gemm_kernel(
    const signed char* __restrict__ qx,   // [2048][1024]
    const signed char* __restrict__ qw,   // [51200][1024]
    const float* __restrict__ bq,         // [51200]
    const unsigned* __restrict__ amax,
    float* __restrict__ outp,             // [2048][50257]
    float* __restrict__ pmax,             // [2048][NB]
    float* __restrict__ psum)             // [2048][NB]
{
  constexpr int BK = 64;  // k-bytes (= k-elements, int8) per tile
  __shared__ signed char sA[2][128 * BK];
  __shared__ signed char sB[2][128 * BK];
  __shared__ float redMax[128][2];
  __shared__ float redSum[128][2];

  const int tid = threadIdx.x;
  const int l = tid & 63;
  const int w = tid >> 6;
  const int wr = w >> 1, wc = w & 1;

  // XCD-bijective decomposition: 6400 blocks = 8 XCDs * 800
  const int bid = blockIdx.x;
  const int vb = (bid & 7) * 800 + (bid >> 3);
  const int nb = vb >> 4;          // column tile 0..399
  const int m0 = (vb & 15) * 128;  // m tile
  const int n0 = nb * 128;

  const float sx = __uint_as_float(amax[0]) * (1.0f / 7.0f);
  const float sw = __uint_as_float(amax[1]) * (1.0f / 7.0f);
  const float scale = sx * sw;

  i32x4 acc[4][4] = {};

  // staging: per wave 2 chunks of 1KB per matrix.
  // chunk c = 16 rows of 64 bytes; lane l -> row c*16 + (l>>2), slot (l&3)
  // LDS dest is linear (lane*16); global source k-slot pre-swizzled by row&3.
  const int srow = (l >> 2);
  const int sslot = (l & 3) ^ (srow & 3);
  const int scol = sslot * 16;

  auto stage = [&](int buf, int k0) {
#pragma unroll
    for (int i = 0; i < 2; ++i) {
      int c = w * 2 + i;
      int row = c * 16 + srow;
      async_copy16(qx + (size_t)(m0 + row) * D_K + k0 + scol,
                   &sA[buf][c * 1024]);
      async_copy16(qw + (size_t)(n0 + row) * D_K + k0 + scol,
                   &sB[buf][c * 1024]);
    }
  };

  stage(0, 0);
  __syncthreads();

  int cur = 0;
  constexpr int NT = D_K / BK;  // 16
  for (int kt = 0; kt < NT; ++kt) {
    if (kt + 1 < NT) stage(cur ^ 1, (kt + 1) * BK);

    i32x4 af[4], bfr[4];
#pragma unroll
    for (int mi = 0; mi < 4; ++mi) {
      int row = wr * 64 + mi * 16 + (l & 15);
      int kb = ((l >> 4) ^ (row & 3)) * 16;
      af[mi] = *(const i32x4*)&sA[cur][row * BK + kb];
    }
#pragma unroll
    for (int ni = 0; ni < 4; ++ni) {
      int row = wc * 64 + ni * 16 + (l & 15);
      int kb = ((l >> 4) ^ (row & 3)) * 16;
      bfr[ni] = *(const i32x4*)&sB[cur][row * BK + kb];
    }
#pragma unroll
    for (int mi = 0; mi < 4; ++mi)
#pragma unroll
      for (int ni = 0; ni < 4; ++ni)
        acc[mi][ni] = __builtin_amdgcn_mfma_i32_16x16x64_i8(
            af[mi], bfr[ni], acc[mi][ni], 0, 0, 0);

    __syncthreads();
    cur ^= 1;
  }

  // ---- epilogue: scale + bias, store logits, fused softmax partials ----
  // C layout: col = n0 + wc*64 + ni*16 + (l&15); row = m0 + wr*64 + mi*16 + (l>>4)*4 + r
  bool valid[4];
  float bb[4];
#pragma unroll
  for (int ni = 0; ni < 4; ++ni) {
    int col = n0 + wc * 64 + ni * 16 + (l & 15);
    valid[ni] = (col < N_VOCAB);
    bb[ni] = valid[ni] ? bq[col] : 0.f;
  }

  float lg[4][4][4];
#pragma unroll
  for (int mi = 0; mi < 4; ++mi)
#pragma unroll
    for (int ni = 0; ni < 4; ++ni)
#pragma unroll
      for (int r = 0; r < 4; ++r)
        lg[mi][ni][r] = (float)acc[mi][ni][r] * scale + bb[ni];

  // store logits
#pragma unroll
  for (int ni = 0; ni < 4; ++ni) {
    if (valid[ni]) {
      int col = n0 + wc * 64 + ni * 16 + (l & 15);
#pragma unroll
      for (int mi = 0; mi < 4; ++mi)
#pragma unroll
        for (int r = 0; r < 4; ++r) {
          int row = m0 + wr * 64 + mi * 16 + (l >> 4) * 4 + r;
          outp[(size_t)row * N_VOCAB + col] = lg[mi][ni][r];
        }
    }
  }

  // per-row max over this wave's 64 cols (reduce ni, then 16 lanes)
  float rmax[4][4];
#pragma unroll
  for (int mi = 0; mi < 4; ++mi)
#pragma unroll
    for (int r = 0; r < 4; ++r) {
      float mval = -3.4e38f;
#pragma unroll
      for (int ni = 0; ni < 4; ++ni)
        if (valid[ni]) mval = fmaxf(mval, lg[mi][ni][r]);
#pragma unroll
      for (int off = 1; off < 16; off <<= 1)
        mval = fmaxf(mval, __shfl_xor(mval, off));
      rmax[mi][r] = mval;
      if ((l & 15) == 0)
        redMax[wr * 64 + mi * 16 + (l >> 4) * 4 + r][wc] = mval;
    }
  __syncthreads();

  // combine across wc pair, sum-exp
#pragma unroll
  for (int mi = 0; mi < 4; ++mi)
#pragma unroll
    for (int r = 0; r < 4; ++r) {
      int rl = wr * 64 + mi * 16 + (l >> 4) * 4 + r;
      float gmax = fmaxf(redMax[rl][0], redMax[rl][1]);
      float s = 0.f;
#pragma unroll
      for (int ni = 0; ni < 4; ++ni)
        if (valid[ni]) s += __expf(lg[mi][ni][r] - gmax);
#pragma unroll
      for (int off = 1; off < 16; off <<= 1)
        s += __shfl_xor(s, off);
      if ((l & 15) == 0) redSum[rl][wc] = s;
      rmax[mi][r] = gmax;
    }
  __syncthreads();

  if (wc == 0 && (l & 15) == 0) {
#pragma unroll
    for (int mi = 0; mi < 4; ++mi)
#pragma unroll
      for (int r = 0; r < 4; ++r) {
        int rl = wr * 64 + mi * 16 + (l >> 4) * 4 + r;
        int rowg = m0 + rl;
        pmax[(size_t)rowg * NB + nb] = rmax[mi][r];
        psum[(size_t)rowg * NB + nb] = redSum[rl][0] + redSum[rl][1];
      }
  }
}

// ---------------- finalize: per-row logZ from partials ----------------
__global__ __launch_bounds__(256) void finalize_kernel(
    const float* __restrict__ pmax, const float* __restrict__ psum,
    float* __restrict__ logz) {
  const int row = blockIdx.x;
  const float* pm = pmax + (size_t)row * NB;
  const float* ps = psum + (size_t)row * NB;
  const int tid = threadIdx.x;
  __shared__ float red[8];

  float m = -3.4e38f;
  for (int i = tid; i < NB; i += 256) m = fmaxf(m, pm[i]);
#pragma unroll
  for (int off = 32; off; off >>= 1) m = fmaxf(m, __shfl_xor(m, off));
  if ((tid & 63) == 0) red[tid >> 6] = m;
  __syncthreads();
  m = fmaxf(fmaxf(red[0], red[1]), fmaxf(red[2], red[3]));

  float s = 0.f;
  for (int i = tid; i < NB; i += 256) s += ps[i] * __expf(pm[i] - m);
#pragma unroll
  for (int off = 32; off; off >>= 1) s += __shfl_xor(s, off);
  if ((tid & 63) == 0) red[4 + (tid >> 6)] = s;
  __syncthreads();
  if (tid == 0) {
    s = red[4] + red[5] + red[6] + red[7];
    logz[row] = m + __logf(s);
  }
}

// ---------------- subtract logZ (in place over flat out) ----------------
__global__ __launch_bounds__(256) void subtract_kernel(
    float4* __restrict__ out, const float* __restrict__ logz, int n4) {
  for (int i = blockIdx.x * blockDim.x + threadIdx.x; i < n4;
       i += gridDim.x * blockDim.x) {
    float4 v = out[i];
    unsigned base = (unsigned)i * 4u;
    v.x -= logz[(base + 0) / N_VOCAB];
    v.y -= logz[(base + 1) / N_VOCAB];
    v.z -= logz[(base + 2) / N_VOCAB];
    v.w -= logz[(base + 3) / N_VOCAB];
    out[i] = v;
  }
}

extern "C" void kernel_launch(void* const* d_in, const int* in_sizes, int n_in,
                              void* d_out, int out_size, void* d_ws,
                              size_t ws_size, hipStream_t stream) {
  const float* x = (const float*)d_in[0];
  const float* W = (const float*)d_in[1];
  const float* b = (const float*)d_in[2];
  float* out = (float*)d_out;

  char* ws = (char*)d_ws;
  unsigned* amax = (unsigned*)ws;                               // 8 B
  float* bq = (float*)(ws + 4096);                              // 204.8 KB
  float* logz = (float*)(ws + (1ull << 20));                    // 8 KB
  float* pmax = (float*)(ws + (2ull << 20));                    // 3.28 MB
  float* psum = (float*)(ws + (6ull << 20));                    // 3.28 MB
  signed char* qx = (signed char*)(ws + (10ull << 20));         // 2 MB
  signed char* qw = (signed char*)(ws + (14ull << 20));         // 52.4 MB

  hipMemsetAsync(amax, 0, 8, stream);

  const int nx4 = (M_ROWS * D_K) / 4;     // 524288
  const int nw4 = (N_VOCAB * D_K) / 4;    // 12865792
  const int nt4 = (N_PAD * D_K) / 4;      // 13107200

  absmax_kernel<<<512, 256, 0, stream>>>((const float4*)x, nx4, amax + 0);
  absmax_kernel<<<2048, 256, 0, stream>>>((const float4*)W, nw4, amax + 1);

  quant_x_kernel<<<nx4 / 256, 256, 0, stream>>>((const float4*)x, (char4*)qx,
                                                amax, nx4);
  quant_w_kernel<<<nt4 / 256, 256, 0, stream>>>((const float4*)W, (char4*)qw,
                                                amax, nw4, nt4);
  bq_kernel<<<(N_PAD + 255) / 256, 256, 0, stream>>>(b, bq, amax);

  gemm_kernel<<<6400, 256, 0, stream>>>(qx, qw, bq, amax, out, pmax, psum);

  finalize_kernel<<<M_ROWS, 256, 0, stream>>>(pmax, psum, logz);

  const int n4 = (M_ROWS * N_VOCAB) / 4;  // 25731584
  subtract_kernel<<<2048, 256, 0, stream>>>((float4*)out, logz, n4);
}